// Round 1
// baseline (230.958 us; speedup 1.0000x reference)
//
#include <hip/hip_runtime.h>

// out[i] = image[i*3 + 0] * w[i*16 + 15], i in [0, 4096*4096)
//
// image: (4096,4096,3) f32 — channel-0 gather, but stride 12B means every
//        sector is needed; load contiguously as 3x float4 per 4 outputs.
// w:     (4096,4096,16) f32 — channel-15 gather, stride 64B: one needed
//        float per 64B sector -> ~1 GiB unavoidable fetch.
// out:   (4096,4096) f32 — coalesced float4 stores.

__global__ __launch_bounds__(256) void MyLayer_kernel(
    const float4* __restrict__ img4,   // image reinterpreted as float4
    const float*  __restrict__ w,
    float4*       __restrict__ out4)
{
    const size_t t    = (size_t)blockIdx.x * blockDim.x + threadIdx.x; // one float4 of output
    const size_t base = t * 4;                                          // first output element

    // image elements (base+k)*3, k=0..3 live in bytes [base*12, base*12+48)
    // = float4 indices t*3 .. t*3+2 (16B-aligned since base*12 = t*48).
    const float4 a = img4[t * 3 + 0];
    const float4 b = img4[t * 3 + 1];
    const float4 c = img4[t * 3 + 2];
    const float i0 = a.x;  // (base+0)*3
    const float i1 = a.w;  // (base+1)*3
    const float i2 = b.z;  // (base+2)*3
    const float i3 = c.y;  // (base+3)*3

    // w channel 15: stride-16 gather (unavoidable sector traffic)
    const float w0 = w[(base + 0) * 16 + 15];
    const float w1 = w[(base + 1) * 16 + 15];
    const float w2 = w[(base + 2) * 16 + 15];
    const float w3 = w[(base + 3) * 16 + 15];

    out4[t] = make_float4(i0 * w0, i1 * w1, i2 * w2, i3 * w3);
}

extern "C" void kernel_launch(void* const* d_in, const int* in_sizes, int n_in,
                              void* d_out, int out_size, void* d_ws, size_t ws_size,
                              hipStream_t stream)
{
    const float* image = (const float*)d_in[0];  // (4096,4096,3) f32
    const float* w     = (const float*)d_in[1];  // (4096,4096,16) f32
    float*       out   = (float*)d_out;          // (4096,4096) f32

    const int n = 4096 * 4096;           // out_size
    const int threads = 256;
    const int blocks  = n / 4 / threads; // 16384, exact (n % 1024 == 0)

    MyLayer_kernel<<<blocks, threads, 0, stream>>>(
        (const float4*)image, w, (float4*)out);
}